// Round 5
// baseline (190.019 us; speedup 1.0000x reference)
//
#include <hip/hip_runtime.h>
#include <math.h>

#define L_SEQ   4096
#define D_INNER 512
#define D_STATE 16
#define DT_RANK 32
#define CHUNK   32
#define NCHUNK  128          // L_SEQ / CHUNK
#define NCH     8192         // D_INNER * D_STATE
#define PPSTRIDE (L_SEQ * 64)   // one split-K partial slab

// ---------------------------------------------------------------------------
// msm_gemm: split-K proj GEMM. proj_part[ks] = x[:, ks*64:+64] @ W_xp[:, ks*64:+64]^T
// grid 512 = (64 row-tiles of 64 rows) x (8 k-splits). 256 thr.
// x-tile xor-swizzled in LDS (conflict-free 4x4 register-tile reads);
// W_xp streamed from global (16 KB slab, L1-resident, amortized over 4 rows).
// ---------------------------------------------------------------------------
__global__ __launch_bounds__(256, 2) void msm_gemm(
    const float* __restrict__ x, const float* __restrict__ W_xp,
    float* __restrict__ proj_part)
{
    __shared__ __align__(16) float sm[64 * 64];
    const int tid = threadIdx.x;
    const int t0 = (blockIdx.x >> 3) * 64;
    const int k0 = (blockIdx.x & 7) * 64;

    // stage x tile 64 rows x 64 k; float4 quad q4 stored at q4 ^ (r>>2)
    #pragma unroll
    for (int i = 0; i < 4; ++i) {
        int e = tid + i * 256;
        int r = e >> 4, q4 = e & 15;
        float4 v = *(const float4*)&x[(size_t)(t0 + r) * D_INNER + k0 + q4 * 4];
        *(float4*)&sm[r * 64 + ((q4 ^ (r >> 2)) << 2)] = v;
    }
    __syncthreads();

    const int rg  = tid >> 4;        // 16 row-groups of 4 rows
    const int cc0 = (tid & 15) * 4;  // 4 output channels
    const int r0  = rg * 4;
    float acc[4][4];
    #pragma unroll
    for (int a = 0; a < 4; ++a)
        #pragma unroll
        for (int b = 0; b < 4; ++b) acc[a][b] = 0.f;

    #pragma unroll 4
    for (int k4 = 0; k4 < 16; ++k4) {
        float4 w0 = *(const float4*)&W_xp[(size_t)(cc0 + 0) * D_INNER + k0 + k4 * 4];
        float4 w1 = *(const float4*)&W_xp[(size_t)(cc0 + 1) * D_INNER + k0 + k4 * 4];
        float4 w2 = *(const float4*)&W_xp[(size_t)(cc0 + 2) * D_INNER + k0 + k4 * 4];
        float4 w3 = *(const float4*)&W_xp[(size_t)(cc0 + 3) * D_INNER + k0 + k4 * 4];
        #pragma unroll
        for (int rr = 0; rr < 4; ++rr) {
            float4 xv = *(const float4*)&sm[(r0 + rr) * 64 + ((k4 ^ rg) << 2)];
            acc[rr][0] += xv.x*w0.x + xv.y*w0.y + xv.z*w0.z + xv.w*w0.w;
            acc[rr][1] += xv.x*w1.x + xv.y*w1.y + xv.z*w1.z + xv.w*w1.w;
            acc[rr][2] += xv.x*w2.x + xv.y*w2.y + xv.z*w2.z + xv.w*w2.w;
            acc[rr][3] += xv.x*w3.x + xv.y*w3.y + xv.z*w3.z + xv.w*w3.w;
        }
    }
    float* pp = proj_part + (size_t)(blockIdx.x & 7) * PPSTRIDE;
    #pragma unroll
    for (int rr = 0; rr < 4; ++rr) {
        float4 o; o.x = acc[rr][0]; o.y = acc[rr][1]; o.z = acc[rr][2]; o.w = acc[rr][3];
        *(float4*)&pp[(size_t)(t0 + r0 + rr) * 64 + cc0] = o;
    }
}

// ---------------------------------------------------------------------------
// msm_chunk: fused (k1b + k2a). Block = (chunk c, 64-d slab), grid (128, 8).
//   - reduce split-K partials for own 32 rows: dtin (rank 32), Bs (16)
//   - dslab 0 also writes Bp/Cp to ws for msm_out
//   - dt = softplus(dtin @ W_dt^T + b) in LDS; also written to dtw (for msm_out)
//   - chunk summary with single-exp clipped-product recurrence -> GTUW
// ---------------------------------------------------------------------------
__global__ __launch_bounds__(256, 4) void msm_chunk(
    const float* __restrict__ x, const float* __restrict__ proj_part,
    const float* __restrict__ W_dt, const float* __restrict__ b_dt,
    const float* __restrict__ A_log,
    const float* __restrict__ alpha_p, const float* __restrict__ beta_logit_p,
    float* __restrict__ dtw, float* __restrict__ BpG, float* __restrict__ CpG,
    float4* __restrict__ GTUW)
{
    __shared__ __align__(16) float xs [CHUNK * 64];
    __shared__ __align__(16) float dts[CHUNK * 64];
    __shared__ __align__(16) float dtin[CHUNK * 36];
    __shared__ __align__(16) float Bs [CHUNK * 20];
    __shared__ __align__(16) float bpw[CHUNK], aib[CHUNK];
    const int tid = threadIdx.x;
    const int c   = blockIdx.x;
    const int d0  = blockIdx.y * 64;

    // stage x (32 rows x 64 d)
    #pragma unroll
    for (int i = 0; i < 2; ++i) {
        int e = tid + i * 256;
        int t = e >> 4, q4 = e & 15;
        *(float4*)&xs[t * 64 + q4 * 4] =
            *(const float4*)&x[(size_t)(c * CHUNK + t) * D_INNER + d0 + q4 * 4];
    }
    // reduce dtin (32 rows x rank 32) from 8 partials
    #pragma unroll
    for (int i = 0; i < 4; ++i) {
        int e = tid + i * 256;
        int r = e >> 5, q = e & 31;
        float s = 0.f;
        #pragma unroll
        for (int p = 0; p < 8; ++p)
            s += proj_part[(size_t)p * PPSTRIDE + (size_t)(c * CHUNK + r) * 64 + q];
        dtin[r * 36 + q] = s;
    }
    // reduce Bs (32 rows x 16 n); dslab 0 also writes Bp/Cp for msm_out
    #pragma unroll
    for (int i = 0; i < 2; ++i) {
        int e = tid + i * 256;
        int r = e >> 4, n = e & 15;
        float sB = 0.f;
        #pragma unroll
        for (int p = 0; p < 8; ++p)
            sB += proj_part[(size_t)p * PPSTRIDE + (size_t)(c * CHUNK + r) * 64 + 32 + n];
        Bs[r * 20 + n] = sB;
        if (blockIdx.y == 0) {
            BpG[(size_t)(c * CHUNK + r) * D_STATE + n] = sB;
            float sC = 0.f;
            #pragma unroll
            for (int p = 0; p < 8; ++p)
                sC += proj_part[(size_t)p * PPSTRIDE + (size_t)(c * CHUNK + r) * 64 + 48 + n];
            CpG[(size_t)(c * CHUNK + r) * D_STATE + n] = sC;
        }
    }
    if (tid < CHUNK) {
        float betaf = 1.f / (1.f + expf(-beta_logit_p[0]));
        double lb = log((double)betaf);
        float bp = (float)exp((double)(c * CHUNK + tid) * lb);
        bpw[tid] = bp;
        aib[tid] = alpha_p[0] / fmaxf(bp, 1e-12f);
    }
    __syncthreads();

    // dt = softplus(dtin @ W_dt^T + b_dt): thread = (rgrp of 8 rows, d-col)
    {
        const int dcol = tid & 63, rgrp = tid >> 6;
        const int gd = d0 + dcol;
        float4 wd[8];
        #pragma unroll
        for (int q = 0; q < 8; ++q)
            wd[q] = *(const float4*)&W_dt[(size_t)gd * DT_RANK + q * 4];
        const float bb = b_dt[gd];
        #pragma unroll
        for (int rr = 0; rr < 8; ++rr) {
            const int r = rgrp * 8 + rr;
            float z = bb;
            #pragma unroll
            for (int q = 0; q < 8; ++q) {
                float4 dn = *(const float4*)&dtin[r * 36 + q * 4];   // broadcast
                z += dn.x*wd[q].x + dn.y*wd[q].y + dn.z*wd[q].z + dn.w*wd[q].w;
            }
            float sp = fmaxf(z, 0.f) + log1pf(expf(-fabsf(z)));
            dts[r * 64 + dcol] = sp;
            dtw[(size_t)(c * CHUNK + r) * D_INNER + gd] = sp;
        }
    }
    __syncthreads();

    // chunk summary: thread = (dl of 64, 4 n's)
    const int dl = tid >> 2, n0 = (tid & 3) << 2;
    float A[4];
    {
        float4 Al = *(const float4*)&A_log[(size_t)(d0 + dl) * D_STATE + n0];
        A[0] = -expf(Al.x); A[1] = -expf(Al.y); A[2] = -expf(Al.z); A[3] = -expf(Al.w);
    }
    float LS[4] = {0,0,0,0}, Ac[4] = {1,1,1,1}, H1[4] = {0,0,0,0}, H2[4] = {0,0,0,0};
    #pragma unroll 4
    for (int j = 0; j < CHUNK; ++j) {
        float dtv = dts[j * 64 + dl];
        float xv  = xs [j * 64 + dl];
        float bp  = bpw[j], ai = aib[j];
        float4 Bv = *(const float4*)&Bs[j * 20 + n0];
        float dx = dtv * xv;
        #pragma unroll
        for (int i = 0; i < 4; ++i) {
            float Bu = dx * ((const float*)&Bv)[i];
            LS[i] = fmaf(ai, Bu, LS[i]);
            float ee = __expf(dtv * A[i]);          // A_bar
            ee = fmaxf(ee, 1e-8f);                  // ref clip(A_c, 1e-8)
            Ac[i] *= ee;                            // A_cum (clipped product)
            float s  = fminf(1.f, Ac[i] * 1e8f);    // A_cum / clip(A_cum,1e-8)
            float t1 = bp * s;
            H1[i] = fmaf(ee, H1[i], t1 * LS[i]);    // -> U
            H2[i] = fmaf(ee, H2[i], t1);            // -> W
        }
    }
    const size_t base = (size_t)c * NCH + (size_t)(d0 + dl) * D_STATE + n0;
    #pragma unroll
    for (int i = 0; i < 4; ++i) {
        float4 o; o.x = LS[i]; o.y = Ac[i]; o.z = H1[i]; o.w = H2[i];
        GTUW[base + i] = o;
    }
}

// ---------------------------------------------------------------------------
// msm_scan: 128-step serial cross-chunk scan, 8192 channels, fp64, depth-8
// prefetch. 32 blocks x 256 thr.
// ---------------------------------------------------------------------------
__global__ __launch_bounds__(256) void msm_scan(
    const float4* __restrict__ GTUW, float2* __restrict__ SC)
{
    const int ch = blockIdx.x * 256 + threadIdx.x;
    double Soff = 0.0, carry = 0.0;
    float4 buf[8];
    #pragma unroll
    for (int p = 0; p < 8; ++p) buf[p] = GTUW[(size_t)p * NCH + ch];
    for (int c = 0; c < NCHUNK; ++c) {
        float4 g = buf[c & 7];
        if (c + 8 < NCHUNK) buf[c & 7] = GTUW[(size_t)(c + 8) * NCH + ch];
        float2 sc; sc.x = (float)Soff; sc.y = (float)carry;
        SC[(size_t)c * NCH + ch] = sc;
        carry = (double)g.y * carry + (double)g.z + Soff * (double)g.w;
        Soff += (double)g.x;
    }
}

// ---------------------------------------------------------------------------
// msm_out: recompute within-chunk state with offsets known, y + D*x.
// Single exp per element: H = ee*H + s*v with H init = carry_prev.
// ---------------------------------------------------------------------------
__global__ __launch_bounds__(256, 4) void msm_out(
    const float* __restrict__ x, const float* __restrict__ dtw,
    const float* __restrict__ BpG, const float* __restrict__ CpG,
    const float* __restrict__ A_log, const float* __restrict__ D_param,
    const float* __restrict__ alpha_p, const float* __restrict__ beta_logit_p,
    const float2* __restrict__ SC, float* __restrict__ out)
{
    __shared__ __align__(16) float xs [CHUNK * 64];
    __shared__ __align__(16) float dts[CHUNK * 64];
    __shared__ __align__(16) float Bs [CHUNK * 20];
    __shared__ __align__(16) float Cs [CHUNK * 20];
    __shared__ __align__(16) float ys [CHUNK * 64];
    __shared__ __align__(16) float bpw[CHUNK], aib[CHUNK];
    const int tid = threadIdx.x;
    const int c   = blockIdx.x;
    const int d0  = blockIdx.y * 64;

    #pragma unroll
    for (int i = 0; i < 2; ++i) {
        int e = tid + i * 256;
        int t = e >> 4, q4 = e & 15;
        *(float4*)&xs [t * 64 + q4 * 4] =
            *(const float4*)&x  [(size_t)(c * CHUNK + t) * D_INNER + d0 + q4 * 4];
        *(float4*)&dts[t * 64 + q4 * 4] =
            *(const float4*)&dtw[(size_t)(c * CHUNK + t) * D_INNER + d0 + q4 * 4];
    }
    #pragma unroll
    for (int i = 0; i < 2; ++i) {
        int e = tid + i * 256;
        int t = e >> 4, n = e & 15;
        Bs[t * 20 + n] = BpG[(size_t)(c * CHUNK + t) * D_STATE + n];
        Cs[t * 20 + n] = CpG[(size_t)(c * CHUNK + t) * D_STATE + n];
    }
    if (tid < CHUNK) {
        float betaf = 1.f / (1.f + expf(-beta_logit_p[0]));
        double lb = log((double)betaf);
        float bp = (float)exp((double)(c * CHUNK + tid) * lb);
        bpw[tid] = bp;
        aib[tid] = alpha_p[0] / fmaxf(bp, 1e-12f);
    }
    __syncthreads();

    const int dl = tid >> 2, n0 = (tid & 3) << 2;
    float A[4];
    {
        float4 Al = *(const float4*)&A_log[(size_t)(d0 + dl) * D_STATE + n0];
        A[0] = -expf(Al.x); A[1] = -expf(Al.y); A[2] = -expf(Al.z); A[3] = -expf(Al.w);
    }
    const size_t base = (size_t)c * NCH + (size_t)(d0 + dl) * D_STATE + n0;
    float So[4], H[4], LS[4] = {0,0,0,0}, Ac[4] = {1,1,1,1};
    #pragma unroll
    for (int i = 0; i < 4; ++i) {
        float2 sc = SC[base + i];
        So[i] = sc.x;
        H[i]  = sc.y;      // carry_prev: H_j = A_cum_j*carry + h_intra_j
    }

    #pragma unroll 4
    for (int j = 0; j < CHUNK; ++j) {
        float dtv = dts[j * 64 + dl];
        float xv  = xs [j * 64 + dl];
        float bp  = bpw[j], ai = aib[j];
        float4 Bv = *(const float4*)&Bs[j * 20 + n0];
        float4 Cv = *(const float4*)&Cs[j * 20 + n0];
        float dx = dtv * xv;
        float contrib = 0.f;
        #pragma unroll
        for (int i = 0; i < 4; ++i) {
            float Bu = dx * ((const float*)&Bv)[i];
            LS[i] = fmaf(ai, Bu, LS[i]);
            float v = bp * (So[i] + LS[i]);         // v_series
            float ee = __expf(dtv * A[i]);
            ee = fmaxf(ee, 1e-8f);
            Ac[i] *= ee;
            float s = fminf(1.f, Ac[i] * 1e8f);
            H[i] = fmaf(ee, H[i], s * v);           // h_full
            contrib = fmaf(H[i], ((const float*)&Cv)[i], contrib);
        }
        contrib += __shfl_xor(contrib, 1);
        contrib += __shfl_xor(contrib, 2);
        if (n0 == 0) ys[j * 64 + dl] = contrib;
    }
    __syncthreads();

    #pragma unroll
    for (int i = 0; i < 2; ++i) {
        int e = tid + i * 256;
        int t = e >> 4, q4 = e & 15;
        float4 yv = *(const float4*)&ys[t * 64 + q4 * 4];
        float4 xv = *(const float4*)&xs[t * 64 + q4 * 4];
        float4 Dv = *(const float4*)&D_param[d0 + q4 * 4];
        float4 o;
        o.x = yv.x + Dv.x * xv.x; o.y = yv.y + Dv.y * xv.y;
        o.z = yv.z + Dv.z * xv.z; o.w = yv.w + Dv.w * xv.w;
        *(float4*)&out[(size_t)(c * CHUNK + t) * D_INNER + d0 + q4 * 4] = o;
    }
}

// ---------------------------------------------------------------------------
extern "C" void kernel_launch(void* const* d_in, const int* in_sizes, int n_in,
                              void* d_out, int out_size, void* d_ws, size_t ws_size,
                              hipStream_t stream)
{
    const float* x          = (const float*)d_in[0];
    const float* W_xp       = (const float*)d_in[1];
    const float* W_dt       = (const float*)d_in[2];
    const float* b_dt       = (const float*)d_in[3];
    const float* A_log      = (const float*)d_in[4];
    const float* D_param    = (const float*)d_in[5];
    const float* alpha      = (const float*)d_in[6];
    const float* beta_logit = (const float*)d_in[7];
    float* out = (float*)d_out;

    float* ws = (float*)d_ws;
    float*  dtw       = ws;                                    // 2,097,152 floats
    float*  BpG       = dtw + (size_t)L_SEQ * D_INNER;         // 65,536
    float*  CpG       = BpG + (size_t)L_SEQ * D_STATE;         // 65,536
    float4* GTUW      = (float4*)(CpG + (size_t)L_SEQ * D_STATE);   // 4,194,304 floats
    float2* SC        = (float2*)((float*)GTUW + (size_t)4 * NCHUNK * NCH); // 2,097,152 floats
    float*  proj_part = (float*)SC + (size_t)2 * NCHUNK * NCH;      // 2,097,152 floats
    // total ≈ 10.6M floats ≈ 42.5 MB (no aliasing)

    msm_gemm <<<512, 256, 0, stream>>>(x, W_xp, proj_part);
    msm_chunk<<<dim3(NCHUNK, 8), 256, 0, stream>>>(
        x, proj_part, W_dt, b_dt, A_log, alpha, beta_logit,
        dtw, BpG, CpG, GTUW);
    msm_scan <<<NCH / 256, 256, 0, stream>>>(GTUW, SC);
    msm_out  <<<dim3(NCHUNK, 8), 256, 0, stream>>>(
        x, dtw, BpG, CpG, A_log, D_param, alpha, beta_logit, SC, out);
}

// Round 6
// 146.779 us; speedup vs baseline: 1.2946x; 1.2946x over previous
//
#include <hip/hip_runtime.h>
#include <math.h>

#define L_SEQ   4096
#define D_INNER 512
#define D_STATE 16
#define DT_RANK 32
#define CHUNK   32
#define NCHUNK  128          // L_SEQ / CHUNK
#define NCH     8192         // D_INNER * D_STATE
#define PPSTRIDE (L_SEQ * 64)   // one split-K partial slab

// ---------------------------------------------------------------------------
// msm_gemm: split-K proj GEMM. proj_part[ks] = x[:, ks*64:+64] @ W_xp[:, ks*64:+64]^T
// grid 512 = (64 row-tiles of 64 rows) x (8 k-splits). 256 thr.
// ---------------------------------------------------------------------------
__global__ __launch_bounds__(256, 2) void msm_gemm(
    const float* __restrict__ x, const float* __restrict__ W_xp,
    float* __restrict__ proj_part)
{
    __shared__ __align__(16) float sm[64 * 64];
    const int tid = threadIdx.x;
    const int t0 = (blockIdx.x >> 3) * 64;
    const int k0 = (blockIdx.x & 7) * 64;

    #pragma unroll
    for (int i = 0; i < 4; ++i) {
        int e = tid + i * 256;
        int r = e >> 4, q4 = e & 15;
        float4 v = *(const float4*)&x[(size_t)(t0 + r) * D_INNER + k0 + q4 * 4];
        *(float4*)&sm[r * 64 + ((q4 ^ (r >> 2)) << 2)] = v;
    }
    __syncthreads();

    const int rg  = tid >> 4;
    const int cc0 = (tid & 15) * 4;
    const int r0  = rg * 4;
    float acc[4][4];
    #pragma unroll
    for (int a = 0; a < 4; ++a)
        #pragma unroll
        for (int b = 0; b < 4; ++b) acc[a][b] = 0.f;

    #pragma unroll 4
    for (int k4 = 0; k4 < 16; ++k4) {
        float4 w0 = *(const float4*)&W_xp[(size_t)(cc0 + 0) * D_INNER + k0 + k4 * 4];
        float4 w1 = *(const float4*)&W_xp[(size_t)(cc0 + 1) * D_INNER + k0 + k4 * 4];
        float4 w2 = *(const float4*)&W_xp[(size_t)(cc0 + 2) * D_INNER + k0 + k4 * 4];
        float4 w3 = *(const float4*)&W_xp[(size_t)(cc0 + 3) * D_INNER + k0 + k4 * 4];
        #pragma unroll
        for (int rr = 0; rr < 4; ++rr) {
            float4 xv = *(const float4*)&sm[(r0 + rr) * 64 + ((k4 ^ rg) << 2)];
            acc[rr][0] += xv.x*w0.x + xv.y*w0.y + xv.z*w0.z + xv.w*w0.w;
            acc[rr][1] += xv.x*w1.x + xv.y*w1.y + xv.z*w1.z + xv.w*w1.w;
            acc[rr][2] += xv.x*w2.x + xv.y*w2.y + xv.z*w2.z + xv.w*w2.w;
            acc[rr][3] += xv.x*w3.x + xv.y*w3.y + xv.z*w3.z + xv.w*w3.w;
        }
    }
    float* pp = proj_part + (size_t)(blockIdx.x & 7) * PPSTRIDE;
    #pragma unroll
    for (int rr = 0; rr < 4; ++rr) {
        float4 o; o.x = acc[rr][0]; o.y = acc[rr][1]; o.z = acc[rr][2]; o.w = acc[rr][3];
        *(float4*)&pp[(size_t)(t0 + r0 + rr) * 64 + cc0] = o;
    }
}

// ---------------------------------------------------------------------------
// msm_chunk: fused (partial-reduce + dt-softplus + chunk summary) -> GTUW
// Block = (chunk c, 64-d slab), grid (128, 8).
// ---------------------------------------------------------------------------
__global__ __launch_bounds__(256, 4) void msm_chunk(
    const float* __restrict__ x, const float* __restrict__ proj_part,
    const float* __restrict__ W_dt, const float* __restrict__ b_dt,
    const float* __restrict__ A_log,
    const float* __restrict__ alpha_p, const float* __restrict__ beta_logit_p,
    float* __restrict__ dtw, float* __restrict__ BpG, float* __restrict__ CpG,
    float4* __restrict__ GTUW)
{
    __shared__ __align__(16) float xs [CHUNK * 64];
    __shared__ __align__(16) float dts[CHUNK * 64];
    __shared__ __align__(16) float dtin[CHUNK * 36];
    __shared__ __align__(16) float Bs [CHUNK * 20];
    __shared__ __align__(16) float bpw[CHUNK], aib[CHUNK];
    const int tid = threadIdx.x;
    const int c   = blockIdx.x;
    const int d0  = blockIdx.y * 64;

    #pragma unroll
    for (int i = 0; i < 2; ++i) {
        int e = tid + i * 256;
        int t = e >> 4, q4 = e & 15;
        *(float4*)&xs[t * 64 + q4 * 4] =
            *(const float4*)&x[(size_t)(c * CHUNK + t) * D_INNER + d0 + q4 * 4];
    }
    #pragma unroll
    for (int i = 0; i < 4; ++i) {
        int e = tid + i * 256;
        int r = e >> 5, q = e & 31;
        float s = 0.f;
        #pragma unroll
        for (int p = 0; p < 8; ++p)
            s += proj_part[(size_t)p * PPSTRIDE + (size_t)(c * CHUNK + r) * 64 + q];
        dtin[r * 36 + q] = s;
    }
    #pragma unroll
    for (int i = 0; i < 2; ++i) {
        int e = tid + i * 256;
        int r = e >> 4, n = e & 15;
        float sB = 0.f;
        #pragma unroll
        for (int p = 0; p < 8; ++p)
            sB += proj_part[(size_t)p * PPSTRIDE + (size_t)(c * CHUNK + r) * 64 + 32 + n];
        Bs[r * 20 + n] = sB;
        if (blockIdx.y == 0) {
            BpG[(size_t)(c * CHUNK + r) * D_STATE + n] = sB;
            float sC = 0.f;
            #pragma unroll
            for (int p = 0; p < 8; ++p)
                sC += proj_part[(size_t)p * PPSTRIDE + (size_t)(c * CHUNK + r) * 64 + 48 + n];
            CpG[(size_t)(c * CHUNK + r) * D_STATE + n] = sC;
        }
    }
    if (tid < CHUNK) {
        float betaf = 1.f / (1.f + expf(-beta_logit_p[0]));
        double lb = log((double)betaf);
        float bp = (float)exp((double)(c * CHUNK + tid) * lb);
        bpw[tid] = bp;
        aib[tid] = alpha_p[0] / fmaxf(bp, 1e-12f);
    }
    __syncthreads();

    {   // dt = softplus(dtin @ W_dt^T + b_dt)
        const int dcol = tid & 63, rgrp = tid >> 6;
        const int gd = d0 + dcol;
        float4 wd[8];
        #pragma unroll
        for (int q = 0; q < 8; ++q)
            wd[q] = *(const float4*)&W_dt[(size_t)gd * DT_RANK + q * 4];
        const float bb = b_dt[gd];
        #pragma unroll
        for (int rr = 0; rr < 8; ++rr) {
            const int r = rgrp * 8 + rr;
            float z = bb;
            #pragma unroll
            for (int q = 0; q < 8; ++q) {
                float4 dn = *(const float4*)&dtin[r * 36 + q * 4];
                z += dn.x*wd[q].x + dn.y*wd[q].y + dn.z*wd[q].z + dn.w*wd[q].w;
            }
            float sp = fmaxf(z, 0.f) + log1pf(expf(-fabsf(z)));
            dts[r * 64 + dcol] = sp;
            dtw[(size_t)(c * CHUNK + r) * D_INNER + gd] = sp;
        }
    }
    __syncthreads();

    const int dl = tid >> 2, n0 = (tid & 3) << 2;
    float A[4];
    {
        float4 Al = *(const float4*)&A_log[(size_t)(d0 + dl) * D_STATE + n0];
        A[0] = -expf(Al.x); A[1] = -expf(Al.y); A[2] = -expf(Al.z); A[3] = -expf(Al.w);
    }
    float LS[4] = {0,0,0,0}, Ac[4] = {1,1,1,1}, H1[4] = {0,0,0,0}, H2[4] = {0,0,0,0};
    #pragma unroll 4
    for (int j = 0; j < CHUNK; ++j) {
        float dtv = dts[j * 64 + dl];
        float xv  = xs [j * 64 + dl];
        float bp  = bpw[j], ai = aib[j];
        float4 Bv = *(const float4*)&Bs[j * 20 + n0];
        float dx = dtv * xv;
        #pragma unroll
        for (int i = 0; i < 4; ++i) {
            float Bu = dx * ((const float*)&Bv)[i];
            LS[i] = fmaf(ai, Bu, LS[i]);
            float ee = __expf(dtv * A[i]);
            ee = fmaxf(ee, 1e-8f);
            Ac[i] *= ee;
            float s  = fminf(1.f, Ac[i] * 1e8f);
            float t1 = bp * s;
            H1[i] = fmaf(ee, H1[i], t1 * LS[i]);
            H2[i] = fmaf(ee, H2[i], t1);
        }
    }
    const size_t base = (size_t)c * NCH + (size_t)(d0 + dl) * D_STATE + n0;
    #pragma unroll
    for (int i = 0; i < 4; ++i) {
        float4 o; o.x = LS[i]; o.y = Ac[i]; o.z = H1[i]; o.w = H2[i];
        GTUW[base + i] = o;
    }
}

// ---------------------------------------------------------------------------
// msm_scan: 128-step serial scan, fp64, STATIC register pipeline (depth 8).
// grid 128 x 64 thr. Inner loop fully unrolled -> buf[] stays in VGPRs.
// ---------------------------------------------------------------------------
__global__ __launch_bounds__(64) void msm_scan(
    const float4* __restrict__ GTUW, float2* __restrict__ SC)
{
    const int ch = blockIdx.x * 64 + threadIdx.x;
    double Soff = 0.0, carry = 0.0;
    float4 buf[8];
    #pragma unroll
    for (int j = 0; j < 8; ++j) buf[j] = GTUW[(size_t)j * NCH + ch];

    for (int g = 0; g < 15; ++g) {
        #pragma unroll
        for (int j = 0; j < 8; ++j) {          // j static -> buf[j] in registers
            const int c = g * 8 + j;
            float4 v = buf[j];
            buf[j] = GTUW[(size_t)(c + 8) * NCH + ch];
            float2 sc; sc.x = (float)Soff; sc.y = (float)carry;
            SC[(size_t)c * NCH + ch] = sc;
            carry = (double)v.y * carry + (double)v.z + Soff * (double)v.w;
            Soff += (double)v.x;
        }
    }
    #pragma unroll
    for (int j = 0; j < 8; ++j) {
        const int c = 120 + j;
        float4 v = buf[j];
        float2 sc; sc.x = (float)Soff; sc.y = (float)carry;
        SC[(size_t)c * NCH + ch] = sc;
        carry = (double)v.y * carry + (double)v.z + Soff * (double)v.w;
        Soff += (double)v.x;
    }
}

// ---------------------------------------------------------------------------
// msm_out: recompute within-chunk state with offsets known, y + D*x.
// ---------------------------------------------------------------------------
__global__ __launch_bounds__(256, 4) void msm_out(
    const float* __restrict__ x, const float* __restrict__ dtw,
    const float* __restrict__ BpG, const float* __restrict__ CpG,
    const float* __restrict__ A_log, const float* __restrict__ D_param,
    const float* __restrict__ alpha_p, const float* __restrict__ beta_logit_p,
    const float2* __restrict__ SC, float* __restrict__ out)
{
    __shared__ __align__(16) float xs [CHUNK * 64];
    __shared__ __align__(16) float dts[CHUNK * 64];
    __shared__ __align__(16) float Bs [CHUNK * 20];
    __shared__ __align__(16) float Cs [CHUNK * 20];
    __shared__ __align__(16) float ys [CHUNK * 64];
    __shared__ __align__(16) float bpw[CHUNK], aib[CHUNK];
    const int tid = threadIdx.x;
    const int c   = blockIdx.x;
    const int d0  = blockIdx.y * 64;

    #pragma unroll
    for (int i = 0; i < 2; ++i) {
        int e = tid + i * 256;
        int t = e >> 4, q4 = e & 15;
        *(float4*)&xs [t * 64 + q4 * 4] =
            *(const float4*)&x  [(size_t)(c * CHUNK + t) * D_INNER + d0 + q4 * 4];
        *(float4*)&dts[t * 64 + q4 * 4] =
            *(const float4*)&dtw[(size_t)(c * CHUNK + t) * D_INNER + d0 + q4 * 4];
    }
    #pragma unroll
    for (int i = 0; i < 2; ++i) {
        int e = tid + i * 256;
        int t = e >> 4, n = e & 15;
        Bs[t * 20 + n] = BpG[(size_t)(c * CHUNK + t) * D_STATE + n];
        Cs[t * 20 + n] = CpG[(size_t)(c * CHUNK + t) * D_STATE + n];
    }
    if (tid < CHUNK) {
        float betaf = 1.f / (1.f + expf(-beta_logit_p[0]));
        double lb = log((double)betaf);
        float bp = (float)exp((double)(c * CHUNK + tid) * lb);
        bpw[tid] = bp;
        aib[tid] = alpha_p[0] / fmaxf(bp, 1e-12f);
    }
    __syncthreads();

    const int dl = tid >> 2, n0 = (tid & 3) << 2;
    float A[4];
    {
        float4 Al = *(const float4*)&A_log[(size_t)(d0 + dl) * D_STATE + n0];
        A[0] = -expf(Al.x); A[1] = -expf(Al.y); A[2] = -expf(Al.z); A[3] = -expf(Al.w);
    }
    const size_t base = (size_t)c * NCH + (size_t)(d0 + dl) * D_STATE + n0;
    float So[4], H[4], LS[4] = {0,0,0,0}, Ac[4] = {1,1,1,1};
    #pragma unroll
    for (int i = 0; i < 4; ++i) {
        float2 sc = SC[base + i];
        So[i] = sc.x;
        H[i]  = sc.y;
    }

    #pragma unroll 4
    for (int j = 0; j < CHUNK; ++j) {
        float dtv = dts[j * 64 + dl];
        float xv  = xs [j * 64 + dl];
        float bp  = bpw[j], ai = aib[j];
        float4 Bv = *(const float4*)&Bs[j * 20 + n0];
        float4 Cv = *(const float4*)&Cs[j * 20 + n0];
        float dx = dtv * xv;
        float contrib = 0.f;
        #pragma unroll
        for (int i = 0; i < 4; ++i) {
            float Bu = dx * ((const float*)&Bv)[i];
            LS[i] = fmaf(ai, Bu, LS[i]);
            float v = bp * (So[i] + LS[i]);
            float ee = __expf(dtv * A[i]);
            ee = fmaxf(ee, 1e-8f);
            Ac[i] *= ee;
            float s = fminf(1.f, Ac[i] * 1e8f);
            H[i] = fmaf(ee, H[i], s * v);
            contrib = fmaf(H[i], ((const float*)&Cv)[i], contrib);
        }
        contrib += __shfl_xor(contrib, 1);
        contrib += __shfl_xor(contrib, 2);
        if (n0 == 0) ys[j * 64 + dl] = contrib;
    }
    __syncthreads();

    #pragma unroll
    for (int i = 0; i < 2; ++i) {
        int e = tid + i * 256;
        int t = e >> 4, q4 = e & 15;
        float4 yv = *(const float4*)&ys[t * 64 + q4 * 4];
        float4 xv = *(const float4*)&xs[t * 64 + q4 * 4];
        float4 Dv = *(const float4*)&D_param[d0 + q4 * 4];
        float4 o;
        o.x = yv.x + Dv.x * xv.x; o.y = yv.y + Dv.y * xv.y;
        o.z = yv.z + Dv.z * xv.z; o.w = yv.w + Dv.w * xv.w;
        *(float4*)&out[(size_t)(c * CHUNK + t) * D_INNER + d0 + q4 * 4] = o;
    }
}

// ---------------------------------------------------------------------------
extern "C" void kernel_launch(void* const* d_in, const int* in_sizes, int n_in,
                              void* d_out, int out_size, void* d_ws, size_t ws_size,
                              hipStream_t stream)
{
    const float* x          = (const float*)d_in[0];
    const float* W_xp       = (const float*)d_in[1];
    const float* W_dt       = (const float*)d_in[2];
    const float* b_dt       = (const float*)d_in[3];
    const float* A_log      = (const float*)d_in[4];
    const float* D_param    = (const float*)d_in[5];
    const float* alpha      = (const float*)d_in[6];
    const float* beta_logit = (const float*)d_in[7];
    float* out = (float*)d_out;

    float* ws = (float*)d_ws;
    float*  dtw     = ws;                                      // 2,097,152 floats
    float*  BpG     = dtw + (size_t)L_SEQ * D_INNER;           // 65,536
    float*  CpG     = BpG + (size_t)L_SEQ * D_STATE;           // 65,536
    float4* GTUW    = (float4*)(CpG + (size_t)L_SEQ * D_STATE);     // 4,194,304 floats
    float*  shared8 = (float*)GTUW + (size_t)4 * NCHUNK * NCH;      // 2,097,152 floats
    // shared8: proj_part (gemm->chunk) then SC (scan->out) — disjoint lifetimes.
    float*  proj_part = shared8;
    float2* SC        = (float2*)shared8;
    // total = 8,519,680 floats ≈ 34.1 MB

    msm_gemm <<<512, 256, 0, stream>>>(x, W_xp, proj_part);
    msm_chunk<<<dim3(NCHUNK, 8), 256, 0, stream>>>(
        x, proj_part, W_dt, b_dt, A_log, alpha, beta_logit,
        dtw, BpG, CpG, GTUW);
    msm_scan <<<NCH / 64, 64, 0, stream>>>(GTUW, SC);
    msm_out  <<<dim3(NCHUNK, 8), 256, 0, stream>>>(
        x, dtw, BpG, CpG, A_log, D_param, alpha, beta_logit, SC, out);
}